// Round 1
// baseline (656.129 us; speedup 1.0000x reference)
//
#include <hip/hip_runtime.h>

// EdgeEmbAttentionAggregator: fused GAT-style aggregation. FLOAT32 I/O.
// Algebraic restructuring: neighs@a_n = neigh_feat@(W2@a_n); h_prime = agg@W2
// where agg = sum_s att[s]*neigh_feat[n,s,:]. Avoids materializing (N*S,64).
//
// R1 changes vs 704.7us baseline:
//  - software prefetch: node n+stride loaded into REGISTERS at iteration top,
//    written to LDS after Phase D's last read of the tile (single LDS buffer;
//    the registers are the double buffer). Loads stay in flight across the
//    whole phase chain instead of being drained at the first barrier.
//  - raw s_barrier + explicit lgkmcnt(0) instead of __syncthreads(), so the
//    compiler's vmcnt(0)-drain before s_barrier does not kill the prefetch.
//  - direct global stores of x / h_edge / h_prime from their finalize phases:
//    removes s_out staging + Phase G. Barriers per node: 6 -> 4.

#define NGS 136   // LDS row stride for 128-wide neigh tile (+8 pad)
#define EES 40    // LDS row stride for 32-wide edge tile

// LDS-visibility barrier WITHOUT the vmcnt(0) drain __syncthreads() emits.
#define BAR() do {                                              \
    asm volatile("s_waitcnt lgkmcnt(0)" ::: "memory");          \
    __builtin_amdgcn_s_barrier();                               \
    asm volatile("" ::: "memory");                              \
} while (0)

// ws layout (fp32): [0:128) w2a = W2 @ a_n ; [128:288) copy of a[0:160)
__global__ __launch_bounds__(256)
void prep_kernel(const float* __restrict__ W2,
                 const float* __restrict__ a,
                 float* __restrict__ ws) {
    const int t = threadIdx.x;
    __shared__ float s_a[160];
    if (t < 160) { float v = a[t]; s_a[t] = v; ws[128 + t] = v; }
    __syncthreads();
    if (t < 128) {
        float p = 0.f;
        #pragma unroll
        for (int d = 0; d < 64; d++) p = fmaf(W2[t * 64 + d], s_a[64 + d], p);
        ws[t] = p;
    }
}

__global__ __launch_bounds__(256)
void gat_kernel(const float* __restrict__ input,
                const float* __restrict__ neigh,
                const float* __restrict__ edge,
                const float* __restrict__ W,
                const float* __restrict__ W2,
                const float* __restrict__ ws,
                float* __restrict__ out,
                int N) {
    const int t = threadIdx.x;
    const int d = t & 63;        // output column this thread owns (x / h')
    const int q = t >> 6;        // which quarter of K (wave id)

    __shared__ float s_ws[288];
    __shared__ float s_in[128];
    __shared__ float s_ng[16 * NGS];
    __shared__ float s_ee[16 * EES];
    __shared__ float s_redA[256];   // Phase A partials (x)
    __shared__ float s_redE[256];   // Phase E partials (h')
    __shared__ float s_agg[128];
    __shared__ float s_sc[16];
    __shared__ float s_att[16];

    // ---- block-invariant setup: W/W2 columns into registers, ws into LDS
    float rW[32], rW2[32];
    {
        const int kb = q * 32;
        #pragma unroll
        for (int k = 0; k < 32; k++) {
            rW[k]  = W [(kb + k) * 64 + d];
            rW2[k] = W2[(kb + k) * 64 + d];
        }
    }
    s_ws[t] = ws[t];
    if (t < 32) s_ws[256 + t] = ws[256 + t];

    const int stride = gridDim.x;
    int n = blockIdx.x;

    // ---- prologue: stage node n into LDS (load -> regs -> LDS)
    {
        const float4* ng4 = (const float4*)(neigh + (size_t)n * 2048);
        const float4 a0 = ng4[t];
        const float4 a1 = ng4[t + 256];
        float4 b0;
        if (t < 128)      b0 = ((const float4*)(edge  + (size_t)n * 512))[t];
        else if (t < 160) b0 = ((const float4*)(input + (size_t)n * 128))[t - 128];
        {
            float* dst = s_ng + (t >> 5) * NGS + ((t & 31) << 2);
            dst[0] = a0.x; dst[1] = a0.y; dst[2] = a0.z; dst[3] = a0.w;
            const int i2 = t + 256;
            float* dst2 = s_ng + (i2 >> 5) * NGS + ((i2 & 31) << 2);
            dst2[0] = a1.x; dst2[1] = a1.y; dst2[2] = a1.z; dst2[3] = a1.w;
        }
        if (t < 128) {
            float* dst = s_ee + (t >> 3) * EES + ((t & 7) << 2);
            dst[0] = b0.x; dst[1] = b0.y; dst[2] = b0.z; dst[3] = b0.w;
        } else if (t < 160) {
            float* dst = s_in + ((t - 128) << 2);
            dst[0] = b0.x; dst[1] = b0.y; dst[2] = b0.z; dst[3] = b0.w;
        }
    }
    BAR();

    for (; n < N; n += stride) {
        // ---- issue prefetch for node n+stride (consumed after Phase D)
        const int nn = n + stride;
        const bool pf = nn < N;
        float4 p_a0, p_a1, p_b0;
        if (pf) {
            const float4* ng4 = (const float4*)(neigh + (size_t)nn * 2048);
            p_a0 = ng4[t];
            p_a1 = ng4[t + 256];
            if (t < 128)      p_b0 = ((const float4*)(edge  + (size_t)nn * 512))[t];
            else if (t < 160) p_b0 = ((const float4*)(input + (size_t)nn * 128))[t - 128];
        }

        // ---- Phase A: x[d] partials (4 threads per d)
        {
            const int kb = q * 32;
            float p = 0.f;
            #pragma unroll
            for (int k = 0; k < 32; k++) p = fmaf(s_in[kb + k], rW[k], p);
            s_redA[t] = p;
        }
        // ---- Phase B: score partials (16 threads per s)
        {
            const int s = t >> 4, g = t & 15;
            float p = 0.f;
            #pragma unroll
            for (int j = 0; j < 8; j++) {
                const int k = g + (j << 4);
                p = fmaf(s_ng[s * NGS + k], s_ws[k], p);        // · w2a
            }
            #pragma unroll
            for (int j = 0; j < 2; j++) {
                const int e = g + (j << 4);
                p = fmaf(s_ee[s * EES + e], s_ws[256 + e], p);  // · a_e
            }
            #pragma unroll
            for (int off = 8; off; off >>= 1) p += __shfl_down(p, off, 16);
            if (g == 0) s_sc[s] = p;
        }
        BAR();

        // ---- Phase C (wave 0): finalize x (store direct), softmax
        if (t < 64) {
            const float x = s_redA[t] + s_redA[t + 64] + s_redA[t + 128] + s_redA[t + 192];
            out[(size_t)n * 160 + t] = x;
            float p = x * s_ws[128 + t];              // a_x
            #pragma unroll
            for (int off = 32; off; off >>= 1) p += __shfl_down(p, off, 64);
            const float sx = __shfl(p, 0, 64);
            if (t < 16) {
                const float sc = sx + s_sc[t];
                const float e = sc > 0.f ? sc : 0.8f * sc;
                float m = e;
                #pragma unroll
                for (int off = 8; off; off >>= 1) m = fmaxf(m, __shfl_xor(m, off, 16));
                const float ex = __expf(e - m);
                float sum = ex;
                #pragma unroll
                for (int off = 8; off; off >>= 1) sum += __shfl_xor(sum, off, 16);
                s_att[t] = ex / sum;
            }
        }
        BAR();

        // ---- Phase D: agg[k] = sum_s att[s]*neigh[s][k]; h_edge (store direct)
        if (t < 128) {
            float p = 0.f;
            #pragma unroll
            for (int s = 0; s < 16; s++) p = fmaf(s_att[s], s_ng[s * NGS + t], p);
            s_agg[t] = p;
        } else if (t < 160) {
            const int e = t - 128;
            float p = 0.f;
            #pragma unroll
            for (int s = 0; s < 16; s++) p = fmaf(s_att[s], s_ee[s * EES + e], p);
            out[(size_t)n * 160 + 128 + e] = p;
        }
        BAR();

        // ---- Phase E: h_prime[d] partials = agg @ W2
        {
            const int kb = q * 32;
            float p = 0.f;
            #pragma unroll
            for (int k = 0; k < 32; k++) p = fmaf(s_agg[kb + k], rW2[k], p);
            s_redE[t] = p;
        }
        // ---- STAGE_WRITE: commit prefetched node into the (now-free) tile.
        // s_ng/s_ee/s_in were last read in Phase D (barrier above separates).
        // Compiler inserts the vmcnt wait for p_* right here, after ~3 phases
        // of latency hiding.
        if (pf) {
            float* dst = s_ng + (t >> 5) * NGS + ((t & 31) << 2);
            dst[0] = p_a0.x; dst[1] = p_a0.y; dst[2] = p_a0.z; dst[3] = p_a0.w;
            const int i2 = t + 256;
            float* dst2 = s_ng + (i2 >> 5) * NGS + ((i2 & 31) << 2);
            dst2[0] = p_a1.x; dst2[1] = p_a1.y; dst2[2] = p_a1.z; dst2[3] = p_a1.w;
            if (t < 128) {
                float* de = s_ee + (t >> 3) * EES + ((t & 7) << 2);
                de[0] = p_b0.x; de[1] = p_b0.y; de[2] = p_b0.z; de[3] = p_b0.w;
            } else if (t < 160) {
                float* di = s_in + ((t - 128) << 2);
                di[0] = p_b0.x; di[1] = p_b0.y; di[2] = p_b0.z; di[3] = p_b0.w;
            }
        }
        BAR();

        // ---- Phase F: finalize h_prime (store direct). No trailing barrier:
        // next iter writes s_redA/s_sc (disjoint from s_redE read here), and
        // the staged tile written above is already barrier-separated.
        if (t < 64)
            out[(size_t)n * 160 + 64 + t] =
                s_redE[t] + s_redE[t + 64] + s_redE[t + 128] + s_redE[t + 192];
    }
}

extern "C" void kernel_launch(void* const* d_in, const int* in_sizes, int n_in,
                              void* d_out, int out_size, void* d_ws, size_t ws_size,
                              hipStream_t stream) {
    const float* input = (const float*)d_in[0];
    const float* neigh = (const float*)d_in[1];
    const float* edge  = (const float*)d_in[2];
    const float* W     = (const float*)d_in[3];
    const float* W2    = (const float*)d_in[4];
    const float* a     = (const float*)d_in[5];
    float* ws = (float*)d_ws;
    float* out = (float*)d_out;

    const int N = in_sizes[0] / 128;   // 50000

    prep_kernel<<<1, 256, 0, stream>>>(W2, a, ws);
    gat_kernel<<<1280, 256, 0, stream>>>(input, neigh, edge, W, W2, ws, out, N);
}